// Round 11
// baseline (192.367 us; speedup 1.0000x reference)
//
#include <hip/hip_runtime.h>
#include <math.h>

#define NB   4
#define NN   2048
#define DD   512
#define NOUT 512
#define NH   8
#define HDIM 64

typedef __attribute__((ext_vector_type(4))) short bf16x4;
typedef __attribute__((ext_vector_type(8))) short bf16x8;
typedef __attribute__((ext_vector_type(4))) float f32x4;
#define MFMA32(a, b, c)  __builtin_amdgcn_mfma_f32_16x16x32_bf16(a, b, c, 0, 0, 0)

typedef const __attribute__((address_space(1))) unsigned int* gas_ptr;
typedef __attribute__((address_space(3))) unsigned int* las_ptr;

#define SCALE2 0.18033688f   /* 8^-1 * log2(e) */

// Fragment-tiled layout: T[blk128][kstep32][row128][32k]
//   flat = blk*65536 + ks*4096 + r*32 + kk

__device__ inline unsigned short f2bf(float f) {
    unsigned int u = __float_as_uint(f);
    u += 0x7fffu + ((u >> 16) & 1u);   // RNE
    return (unsigned short)(u >> 16);
}

// pack two fp32 -> two bf16 (truncation) in ONE v_perm
__device__ inline unsigned int pack_trunc(float lo, float hi) {
    return __builtin_amdgcn_perm(__float_as_uint(hi), __float_as_uint(lo), 0x07060302u);
}

// Raw v_exp_f32 (2^x) via the COMPILER-VISIBLE builtin (round-5 win: VALU
// busy halved vs OCML exp2f). Must NOT be inline asm: MFMA->VALU RAW hazard
// is software-managed and skipped for INLINEASM readers (round-4 corruption).
#if __has_builtin(__builtin_amdgcn_exp2f)
#define EXP2(x) __builtin_amdgcn_exp2f(x)
#else
#define EXP2(x) exp2f(x)
#endif

// LDS 16B-block swizzle for staged GEMM tiles: involution (XORs bits 3-5
// into bits 0-2, disjoint) => stage source block SWZB(d) into LDS block d,
// read global block g at LDS block SWZB(g).
#define SWZB(g) ((g) ^ (((g) >> 3) & 7))

// ---------------------------------------------------------------------------
// prep (r7 form restored — r10's aux-packing into gemm_qkv was neutral-to-
// negative): convx (x -> bf16, fragment-tiled), transW (all 4 weights),
// amask (adj -> u32 AND-words).
// ---------------------------------------------------------------------------
__global__ __launch_bounds__(256) void prep(
    const float* __restrict__ x, unsigned short* __restrict__ xt,
    const float* __restrict__ W0, const float* __restrict__ W1,
    const float* __restrict__ W2, const float* __restrict__ W3,
    unsigned short* __restrict__ Tqkv, unsigned short* __restrict__ To,
    const int* __restrict__ adj, unsigned int* __restrict__ amaskW)
{
    const int blk = blockIdx.x;
    const int t   = threadIdx.x;

    if (blk < 2048) {                       // ---- convx -> tiled ----
        const int i = (blk * 256 + t) * 8;
        const int m = i >> 9, k = i & 511;
        float4 a = *(const float4*)(x + i);
        float4 b = *(const float4*)(x + i + 4);
        ushort4 u0, u1;
        u0.x = f2bf(a.x); u0.y = f2bf(a.y); u0.z = f2bf(a.z); u0.w = f2bf(a.w);
        u1.x = f2bf(b.x); u1.y = f2bf(b.y); u1.z = f2bf(b.z); u1.w = f2bf(b.w);
        unsigned short* dst = xt + ((size_t)(m >> 7) * 65536)
                                 + (k >> 5) * 4096 + (m & 127) * 32 + (k & 31);
        *(ushort4*)dst       = u0;
        *(ushort4*)(dst + 4) = u1;
        return;
    }
    if (blk < 2304) {                       // ---- transW -> tiled ----
        __shared__ float tile[64][65];
        const int idx = blk - 2048;
        const int z = idx >> 6, rem = idx & 63;
        const float* W;
        switch (z) {
            case 0:  W = W0; break;
            case 1:  W = W1; break;
            case 2:  W = W2; break;
            default: W = W3; break;
        }
        unsigned short* T = (z < 3) ? Tqkv : To;
        const int ngbase  = (z < 3) ? z * 512 : 0;
        const int k0 = (rem & 7) * 64, n0 = (rem >> 3) * 64;
        const int r = t >> 6, c = t & 63;
#pragma unroll
        for (int rep = 0; rep < 16; ++rep) {
            const int row = rep * 4 + r;
            tile[row][c] = W[(size_t)(k0 + row) * NOUT + n0 + c];
        }
        __syncthreads();
        const int k  = k0 + c;
        const int ks = k >> 5, kk = k & 31;
#pragma unroll
        for (int rep = 0; rep < 16; ++rep) {
            const int row = rep * 4 + r;          // n within this matrix
            const int ng  = ngbase + n0 + row;
            T[((size_t)(ng >> 7) * 65536) + ks * 4096 + (ng & 127) * 32 + kk]
                = f2bf(tile[c][row]);
        }
        return;
    }
    // ---- amask: 4 u32 words (8 keys) per thread ----
    {
        const int gid  = (blk - 2304) * 256 + t;   // 0..524287
        const int w0   = gid * 4;
        const int qrow = w0 >> 10;
        const int wloc = w0 & 1023;
        const int kb0  = wloc * 2;
        int4 a0 = *(const int4*)(adj + (size_t)qrow * NN + kb0);
        int4 a1 = *(const int4*)(adj + (size_t)qrow * NN + kb0 + 4);
        uint4 m;
        m.x = (a0.x ? 0xFFFFu : 0u) | (a0.y ? 0xFFFF0000u : 0u);
        m.y = (a0.z ? 0xFFFFu : 0u) | (a0.w ? 0xFFFF0000u : 0u);
        m.z = (a1.x ? 0xFFFFu : 0u) | (a1.y ? 0xFFFF0000u : 0u);
        m.w = (a1.z ? 0xFFFFu : 0u) | (a1.w ? 0xFFFF0000u : 0u);
        *(uint4*)(amaskW + (size_t)qrow * 1024 + wloc) = m;
    }
}

// ---------------------------------------------------------------------------
// Staged GEMM (m97 structure): global_load_lds double-buffered K-loop.
// (r7: this took non-attn 131 -> 121 us. Kept verbatim.)
// ---------------------------------------------------------------------------
#define GTS_STAGE(ks, Ab, Bb, NB16)                                            \
    {                                                                          \
        const unsigned short* As_ = Asrc + (ks) * 4096;                        \
        const unsigned short* Bs_ = Bsrc + (ks) * 4096;                        \
        __builtin_amdgcn_global_load_lds(                                      \
            (gas_ptr)(As_ + (wave * 64 + lswz) * 8),                           \
            (las_ptr)((Ab) + wave * 512), 16, 0, 0);                           \
        __builtin_amdgcn_global_load_lds(                                      \
            (gas_ptr)(As_ + (256 + wave * 64 + lswz) * 8),                     \
            (las_ptr)((Ab) + 2048 + wave * 512), 16, 0, 0);                    \
        __builtin_amdgcn_global_load_lds(                                      \
            (gas_ptr)(Bs_ + (wave * 64 + lswz) * 8),                           \
            (las_ptr)((Bb) + wave * 512), 16, 0, 0);                           \
        if ((NB16) == 512)                                                     \
            __builtin_amdgcn_global_load_lds(                                  \
                (gas_ptr)(Bs_ + (256 + wave * 64 + lswz) * 8),                 \
                (las_ptr)((Bb) + 2048 + wave * 512), 16, 0, 0);                \
    }

#define GT_MFMA(Af, Bf, NTC)                                                   \
    _Pragma("unroll")                                                          \
    for (int mt = 0; mt < 4; ++mt)                                             \
        _Pragma("unroll")                                                      \
        for (int nt = 0; nt < NTC; ++nt)                                       \
            acc[mt][nt] = MFMA32(Af[mt], Bf[nt], acc[mt][nt]);

#define GTS_FRAGS(Ab, Bb, NTC)                                                 \
    bf16x8 aF[4], bF[NTC];                                                     \
    _Pragma("unroll")                                                          \
    for (int mt = 0; mt < 4; ++mt) aF[mt] = *(const bf16x8*)&(Ab)[aOff[mt]];   \
    _Pragma("unroll")                                                          \
    for (int nt = 0; nt < NTC; ++nt) bF[nt] = *(const bf16x8*)&(Bb)[bOff[nt]];

#define GTS_LOOP(NTC, NB16, sA0, sB0, sA1, sB1)                                \
    const int lswz = lane ^ ((lane >> 3) & 7);                                 \
    int aOff[4], bOff[NTC];                                                    \
    _Pragma("unroll")                                                          \
    for (int mt = 0; mt < 4; ++mt)                                             \
        aOff[mt] = SWZB((wm + mt * 16 + l16) * 4 + quad) * 8;                  \
    _Pragma("unroll")                                                          \
    for (int nt = 0; nt < NTC; ++nt)                                           \
        bOff[nt] = SWZB((wn + nt * 16 + l16) * 4 + quad) * 8;                  \
    f32x4 acc[4][NTC];                                                         \
    _Pragma("unroll")                                                          \
    for (int mt = 0; mt < 4; ++mt)                                             \
        _Pragma("unroll")                                                      \
        for (int nt = 0; nt < NTC; ++nt) acc[mt][nt] = (f32x4){0.f, 0.f, 0.f, 0.f}; \
    GTS_STAGE(0, sA0, sB0, NB16);                                              \
    for (int kk = 0; kk < 8; ++kk) {                                           \
        __syncthreads();                                                       \
        GTS_STAGE(2 * kk + 1, sA1, sB1, NB16);                                 \
        { GTS_FRAGS(sA0, sB0, NTC); GT_MFMA(aF, bF, NTC); }                    \
        __syncthreads();                                                       \
        if (kk < 7) GTS_STAGE(2 * kk + 2, sA0, sB0, NB16);                     \
        { GTS_FRAGS(sA1, sB1, NTC); GT_MFMA(aF, bF, NTC); }                    \
    }

// ---------------------------------------------------------------------------
// Fused QKV GEMM (staged). Coalesced epilogue via per-wave LDS round-trip.
// ---------------------------------------------------------------------------
__global__ __launch_bounds__(256, 3) void gemm_qkv(
    const unsigned short* __restrict__ Atil,
    const unsigned short* __restrict__ Wtil,
    const float* __restrict__ bq, const float* __restrict__ bk,
    const float* __restrict__ bv,
    unsigned short* __restrict__ qo, unsigned short* __restrict__ ko,
    unsigned short* __restrict__ vto)
{
    __shared__ unsigned short smem[16384];   // A0|B0|A1|B1 (32 KB), eps alias
    unsigned short* sA0 = smem;
    unsigned short* sB0 = smem + 4096;
    unsigned short* sA1 = smem + 8192;
    unsigned short* sB1 = smem + 12288;

    const int t = threadIdx.x, wave = t >> 6, lane = t & 63;
    const int quad = lane >> 4, l16 = lane & 15;
    const int n0 = blockIdx.x * 128, m0 = blockIdx.y * 128;
    const int wm = (wave & 1) * 64, wn = (wave >> 1) * 64;
    const unsigned short* Asrc = Atil + (size_t)blockIdx.y * 65536;
    const unsigned short* Bsrc = Wtil + (size_t)blockIdx.x * 65536;

    GTS_LOOP(4, 512, sA0, sB0, sA1, sB1);

    const int seg   = n0 >> 9;           // 0:q 1:k 2:v
    const int nloc0 = n0 & 511;
    const float* bp = (seg == 0) ? bq : (seg == 1) ? bk : bv;
    unsigned short* dst3 = (seg == 0) ? qo : (seg == 1) ? ko : vto;
    const int h = (nloc0 + wn) >> 6;     // wave's 64 cols = one head

    float bias4[4];
#pragma unroll
    for (int nt = 0; nt < 4; ++nt) bias4[nt] = bp[nloc0 + wn + nt * 16 + l16];

    __syncthreads();                     // staging reads done; alias eps
    unsigned short* Lo = smem + wave * 2560;
#pragma unroll
    for (int mt = 0; mt < 4; ++mt) {
        if (seg < 2) {
            // region [16 m][72 d-pad], C-layout scatter -> row-coalesced out
#pragma unroll
            for (int nt = 0; nt < 4; ++nt)
#pragma unroll
                for (int r = 0; r < 4; ++r) {
                    float val = acc[mt][nt][r] + bias4[nt];
                    if (seg == 0) val *= SCALE2;
                    Lo[(quad * 4 + r) * 72 + nt * 16 + l16] = f2bf(val);
                }
#pragma unroll
            for (int pass = 0; pass < 2; ++pass) {
                const int row = pass * 8 + (lane >> 3);
                const int mg  = m0 + wm + mt * 16 + row;
                const int bb  = mg >> 11, n = mg & (NN - 1);
                bf16x8 v = *(const bf16x8*)&Lo[row * 72 + (lane & 7) * 8];
                *(bf16x8*)(dst3 + ((size_t)(bb * NH + h) * NN + n) * HDIM
                           + (lane & 7) * 8) = v;
            }
        } else {
            // region [64 d][40-pad m], transposed scatter -> d-row out
#pragma unroll
            for (int nt = 0; nt < 4; ++nt)
#pragma unroll
                for (int r = 0; r < 4; ++r) {
                    const float val = acc[mt][nt][r] + bias4[nt];
                    Lo[(nt * 16 + l16) * 40 + quad * 4 + r] = f2bf(val);
                }
            const int d  = lane;
            const int mg = m0 + wm + mt * 16;
            const int bb = mg >> 11, n = mg & (NN - 1);
            unsigned short* dr = dst3 + ((size_t)(bb * NH + h) * HDIM + d) * NN + n;
            *(bf16x8*)dr       = *(const bf16x8*)&Lo[d * 40];
            *(bf16x8*)(dr + 8) = *(const bf16x8*)&Lo[d * 40 + 8];
        }
    }
}

// ---------------------------------------------------------------------------
// O-projection GEMM (staged): 128x64 tiles, out fp32 [8192,512]
// ---------------------------------------------------------------------------
__global__ __launch_bounds__(256, 3) void gemm_o(
    const unsigned short* __restrict__ Atil,
    const unsigned short* __restrict__ Wtil,
    const float* __restrict__ bias,
    float* __restrict__ C)
{
    __shared__ unsigned short smem[12288];   // A0(8K)|B0(4K)|A1(8K)|B1(4K)
    unsigned short* sA0 = smem;
    unsigned short* sB0 = smem + 4096;
    unsigned short* sA1 = smem + 6144;
    unsigned short* sB1 = smem + 10240;

    const int t = threadIdx.x, wave = t >> 6, lane = t & 63;
    const int quad = lane >> 4, l16 = lane & 15;
    const int n0 = blockIdx.x * 64, m0 = blockIdx.y * 128;
    const int wm = (wave & 1) * 64, wn = (wave >> 1) * 32;
    const unsigned short* Asrc = Atil + (size_t)blockIdx.y * 65536;
    const unsigned short* Bsrc = Wtil + (size_t)(n0 >> 7) * 65536 + (n0 & 64) * 32;

    GTS_LOOP(2, 256, sA0, sB0, sA1, sB1);

    float bias2[2];
#pragma unroll
    for (int nt = 0; nt < 2; ++nt) bias2[nt] = bias[n0 + wn + nt * 16 + l16];

#pragma unroll
    for (int mt = 0; mt < 4; ++mt)
#pragma unroll
        for (int nt = 0; nt < 2; ++nt) {
            const int col = n0 + wn + nt * 16 + l16;
#pragma unroll
            for (int r = 0; r < 4; ++r) {
                const int row = m0 + wm + mt * 16 + quad * 4 + r;
                C[(size_t)row * NOUT + col] = acc[mt][nt][r] + bias2[nt];
            }
        }
}

// ---------------------------------------------------------------------------
// MFMA flash attention v10: v6's per-wave structure, QBLK=64 / 4 waves /
// 1024 blocks. Occupancy was GRID-limited at 2 blocks/CU (512 blocks); the
// only mechanism that reliably hides the barrier drain is independent
// co-resident blocks (m114; all explicit pipelining failed). This quarters
// the q-tile: 4 blocks/CU x 4 waves = same 16 waves/CU but FOUR independent
// barrier domains instead of two, with smaller (4-wave) barriers. Per-wave
// register state and tile() are bit-identical to v6 (64 VGPR); staging uses
// r6's proven 4-op macro (each wave stages 16 K + 16 V rows). Cost: K/V
// re-read doubles per (b,h) — benign, HBM at 20% of peak.
// ---------------------------------------------------------------------------
__global__ __launch_bounds__(256, 4) void attn_mfma(
    const unsigned short* __restrict__ qg,
    const unsigned short* __restrict__ kg,
    const unsigned short* __restrict__ vt,
    const unsigned int* __restrict__ amask,   // [q][1024] u32 AND-words
    unsigned short* __restrict__ aot)
{
    // 32 KB: K/V double-buffer during loop; pair-reduction F (18 KB) +
    // epilogue Lo regions aliased afterwards.
    __shared__ unsigned short smem[16384];
    unsigned short* Ka = smem;            // [64][64]
    unsigned short* Va = smem + 4096;
    unsigned short* Kb = smem + 8192;
    unsigned short* Vb = smem + 12288;

    const int t    = threadIdx.x;
    const int wave = t >> 6;             // 0..3
    const int lane = t & 63;
    const int quad = lane >> 4;
    const int l16  = lane & 15;
    const int pair = wave >> 1;          // 0..1: q-rows pair*32..+31
    const int hk   = wave & 1;           // key half within each 64-key tile

    const int qt = blockIdx.x, h = blockIdx.y, b = blockIdx.z;
    const int bh = b * NH + h;
    const int q0 = qt * 64;

    const unsigned short* kbase  = kg + (size_t)bh * NN * HDIM;
    const unsigned short* vtbase = vt + (size_t)bh * HDIM * NN;

    // DMA swizzle (16B blocks): physical blk = logical blk ^ (row & 7)
    const int drow = lane >> 3;
    const int dblk = (lane & 7) ^ drow;
    // key permutation: physical LDS row p holds logical key L(p).
    // Each wave stages 16 rows: p0 = wave*16+drow and p1 = p0+8.
    const int p0_ = wave * 16 + drow;
    const int p1_ = p0_ + 8;
    const int Lp0 = (p0_ & 32) + ((p0_ >> 2) & 3) * 8 + ((p0_ >> 4) & 1) * 4 + (p0_ & 3);
    const int Lp1 = (p1_ & 32) + ((p1_ >> 2) & 3) * 8 + ((p1_ >> 4) & 1) * 4 + (p1_ & 3);

    // fragment-read swizzle offsets
    const int sw  = l16 & 7;
    const int bo0 = (quad ^ sw) * 8;         // K d-chunk0 (16B)
    const int bo1 = bo0 ^ 32;                // K d-chunk1

#define ATT_ISSUE(kt, Kd, Vd)                                                  \
    {                                                                          \
        const int r0 = wave * 16;                                              \
        __builtin_amdgcn_global_load_lds(                                      \
            (gas_ptr)(kbase + (size_t)((kt) * 64 + Lp0) * HDIM + dblk * 8),    \
            (las_ptr)(Kd + r0 * 64), 16, 0, 0);                                \
        __builtin_amdgcn_global_load_lds(                                      \
            (gas_ptr)(kbase + (size_t)((kt) * 64 + Lp1) * HDIM + dblk * 8),    \
            (las_ptr)(Kd + (r0 + 8) * 64), 16, 0, 0);                          \
        __builtin_amdgcn_global_load_lds(                                      \
            (gas_ptr)(vtbase + (size_t)(r0 + drow) * NN + (kt) * 64 + dblk * 8), \
            (las_ptr)(Vd + r0 * 64), 16, 0, 0);                                \
        __builtin_amdgcn_global_load_lds(                                      \
            (gas_ptr)(vtbase + (size_t)(r0 + 8 + drow) * NN + (kt) * 64 + dblk * 8), \
            (las_ptr)(Vd + (r0 + 8) * 64), 16, 0, 0);                          \
    }

    // Q B-fragments for the pair's TWO 16-row q-groups
    const int myq0 = q0 + pair * 32 + l16;        // g=0
    const int myq1 = myq0 + 16;                   // g=1
    const unsigned short* qrow0 = qg + ((size_t)bh * NN + myq0) * HDIM;
    const unsigned short* qrow1 = qg + ((size_t)bh * NN + myq1) * HDIM;
    const bf16x8 bQ0g0 = *(const bf16x8*)(qrow0 + quad * 8);
    const bf16x8 bQ1g0 = *(const bf16x8*)(qrow0 + quad * 8 + 32);
    const bf16x8 bQ0g1 = *(const bf16x8*)(qrow1 + quad * 8);
    const bf16x8 bQ1g1 = *(const bf16x8*)(qrow1 + quad * 8 + 32);

    const unsigned int* mrow0 = amask + (size_t)myq0 * 1024 + quad * 4;
    const unsigned int* mrow1 = amask + (size_t)myq1 * 1024 + quad * 4;
#define MLOAD(kt, g) (*(const uint4*)(((g) ? mrow1 : mrow0) + (kt) * 32 + hk * 16))

    bf16x8 ones8;
#pragma unroll
    for (int j = 0; j < 8; ++j) ones8[j] = (short)0x3F80;

    f32x4 O[4][2];                // [dt 16-d group][q-group]
#pragma unroll
    for (int dt = 0; dt < 4; ++dt)
#pragma unroll
        for (int g = 0; g < 2; ++g) O[dt][g] = (f32x4){0.f, 0.f, 0.f, 0.f};
    f32x4 lacc[2];
    lacc[0] = (f32x4){0.f, 0.f, 0.f, 0.f};
    lacc[1] = (f32x4){0.f, 0.f, 0.f, 0.f};

    auto tile = [&](const unsigned short* Ks, const unsigned short* Vs,
                    uint4 mwg0, uint4 mwg1) {
        // K fragments for this wave's 32-key half, read ONCE, used for 2 q-groups
        bf16x8 aK[2][2];          // [kg 16-key group][d-chunk]
#pragma unroll
        for (int kg = 0; kg < 2; ++kg) {
            const int nt = hk * 2 + kg;
            aK[kg][0] = *(const bf16x8*)&Ks[(nt * 16 + l16) * 64 + bo0];
            aK[kg][1] = *(const bf16x8*)&Ks[(nt * 16 + l16) * 64 + bo1];
        }
        bf16x8 Pt[2];
#pragma unroll
        for (int g = 0; g < 2; ++g) {
            const uint4 mw = g ? mwg1 : mwg0;
            const bf16x8 q0f = g ? bQ0g1 : bQ0g0;
            const bf16x8 q1f = g ? bQ1g1 : bQ1g0;
            union { unsigned int u[4]; bf16x8 v; } cv;
#pragma unroll
            for (int kg = 0; kg < 2; ++kg) {
                f32x4 s = (f32x4){0.f, 0.f, 0.f, 0.f};
                s = MFMA32(aK[kg][0], q0f, s);
                s = MFMA32(aK[kg][1], q1f, s);
                const float p0 = EXP2(s[0]);
                const float p1 = EXP2(s[1]);
                const float p2 = EXP2(s[2]);
                const float p3 = EXP2(s[3]);
                cv.u[kg * 2 + 0] = pack_trunc(p0, p1) & (kg ? mw.z : mw.x);
                cv.u[kg * 2 + 1] = pack_trunc(p2, p3) & (kg ? mw.w : mw.y);
            }
            Pt[g] = cv.v;
            lacc[g] = MFMA32(ones8, Pt[g], lacc[g]);
        }
#pragma unroll
        for (int dt = 0; dt < 4; ++dt) {
            bf16x8 aV = *(const bf16x8*)
                &Vs[(dt * 16 + l16) * 64 + (((hk * 4 + quad) ^ sw) * 8)];
#pragma unroll
            for (int g = 0; g < 2; ++g)
                O[dt][g] = MFMA32(aV, Pt[g], O[dt][g]);
        }
    };

    uint4 mA0 = MLOAD(0, 0), mA1 = MLOAD(0, 1);
    uint4 mB0, mB1;
    ATT_ISSUE(0, Ka, Va);
    for (int kk = 0; kk < 16; ++kk) {
        __syncthreads();
        ATT_ISSUE(2 * kk + 1, Kb, Vb);
        mB0 = MLOAD(2 * kk + 1, 0); mB1 = MLOAD(2 * kk + 1, 1);
        tile(Ka, Va, mA0, mA1);
        __syncthreads();
        if (kk < 15) {
            ATT_ISSUE(2 * kk + 2, Ka, Va);
            mA0 = MLOAD(2 * kk + 2, 0); mA1 = MLOAD(2 * kk + 2, 1);
        }
        tile(Kb, Vb, mB0, mB1);
    }
    __syncthreads();   // all waves done reading K/V buffers

    // ---- cross-pair reduction: hk=1 partials -> LDS -> hk=0 accumulates ----
    // F region: [pair(2)][lane][36 f32] = 18 KB (aliases K/V buffers)
    float* F   = (float*)smem;
    float* myF = F + ((size_t)pair * 64 + lane) * 36;
    if (hk == 1) {
#pragma unroll
        for (int dt = 0; dt < 4; ++dt)
#pragma unroll
            for (int g = 0; g < 2; ++g)
                *(f32x4*)(myF + dt * 8 + g * 4) = O[dt][g];
        myF[32] = lacc[0][0];
        myF[33] = lacc[1][0];
    }
    __syncthreads();
    float inv0 = 0.f, inv1 = 0.f;
    if (hk == 0) {
#pragma unroll
        for (int dt = 0; dt < 4; ++dt)
#pragma unroll
            for (int g = 0; g < 2; ++g) {
                const f32x4 o2 = *(const f32x4*)(myF + dt * 8 + g * 4);
                O[dt][g] += o2;
            }
        inv0 = 1.f / (lacc[0][0] + myF[32]);
        inv1 = 1.f / (lacc[1][0] + myF[33]);
    }
    __syncthreads();   // F consumed; smem reusable for Lo regions

    // ---- epilogue (hk=0 waves): O^T -> per-group LDS region -> tiled out ----
    if (hk == 0) {
#pragma unroll
        for (int g = 0; g < 2; ++g) {
            const float inv = g ? inv1 : inv0;
            unsigned short* Lo = smem + (pair * 2 + g) * 1152;
#pragma unroll
            for (int dt = 0; dt < 4; ++dt) {
                const float v0 = O[dt][g][0] * inv, v1 = O[dt][g][1] * inv;
                const float v2 = O[dt][g][2] * inv, v3 = O[dt][g][3] * inv;
                *(unsigned int*)&Lo[l16 * 72 + dt * 16 + quad * 4]     = pack_trunc(v0, v1);
                *(unsigned int*)&Lo[l16 * 72 + dt * 16 + quad * 4 + 2] = pack_trunc(v2, v3);
            }
            const int rr = lane >> 2;
            const int qq = q0 + pair * 32 + g * 16 + rr;
            const int m  = b * NN + qq;
            const int mb = m >> 7, r = m & 127;
#pragma unroll
            for (int i = 0; i < 2; ++i) {
                const int ch = (lane & 3) + 4 * i;            // 0..7 (d = ch*8)
                const int ks = h * 2 + (ch >> 2);
                bf16x8 val = *(const bf16x8*)&Lo[rr * 72 + ch * 8];
                *(bf16x8*)(aot + (size_t)mb * 65536 + ks * 4096 + r * 32 + (ch & 3) * 8) = val;
            }
        }
    }
#undef ATT_ISSUE
#undef MLOAD
}

// ---------------------------------------------------------------------------
extern "C" void kernel_launch(void* const* d_in, const int* in_sizes, int n_in,
                              void* d_out, int out_size, void* d_ws, size_t ws_size,
                              hipStream_t stream)
{
    const float* x   = (const float*)d_in[0];
    const int*   adj = (const int*)  d_in[1];
    const float* Wq  = (const float*)d_in[2];
    const float* bq  = (const float*)d_in[3];
    const float* Wk  = (const float*)d_in[4];
    const float* bk  = (const float*)d_in[5];
    const float* Wv  = (const float*)d_in[6];
    const float* bv  = (const float*)d_in[7];
    const float* Wo  = (const float*)d_in[8];
    const float* bo  = (const float*)d_in[9];
    float* out = (float*)d_out;

    const size_t qkv_elems = (size_t)NB * NH * NN * HDIM;   // 4,194,304
    unsigned short* xt    = (unsigned short*)d_ws;           // x tiled; reused as aot
    unsigned short* q     = xt   + qkv_elems;
    unsigned short* kb    = q    + qkv_elems;
    unsigned short* vtb   = kb   + qkv_elems;
    unsigned short* tWqkv = vtb  + qkv_elems;                // 1536x512 tiled
    unsigned short* tWo   = tWqkv + (size_t)3 * DD * NOUT;   // 512x512 tiled
    unsigned int*   amaskW = (unsigned int*)(tWo + (size_t)DD * NOUT);  // 8MB
    unsigned short* aot   = xt;                              // alias (xt dead after QKV)

    prep<<<dim3(4352), 256, 0, stream>>>(x, xt, Wq, Wk, Wv, Wo,
                                         tWqkv, tWo, adj, amaskW);

    gemm_qkv<<<dim3(12, 64), 256, 0, stream>>>(xt, tWqkv, bq, bk, bv, q, kb, vtb);

    attn_mfma<<<dim3(NN / 64, NH, NB), 256, 0, stream>>>(q, kb, vtb, amaskW, aot);

    gemm_o<<<dim3(8, 64), 256, 0, stream>>>(aot, tWo, bo, out);
}

// Round 12
// 174.038 us; speedup vs baseline: 1.1053x; 1.1053x over previous
//
#include <hip/hip_runtime.h>
#include <math.h>

#define NB   4
#define NN   2048
#define DD   512
#define NOUT 512
#define NH   8
#define HDIM 64

typedef __attribute__((ext_vector_type(4))) short bf16x4;
typedef __attribute__((ext_vector_type(8))) short bf16x8;
typedef __attribute__((ext_vector_type(4))) float f32x4;
#define MFMA32(a, b, c)  __builtin_amdgcn_mfma_f32_16x16x32_bf16(a, b, c, 0, 0, 0)

typedef const __attribute__((address_space(1))) unsigned int* gas_ptr;
typedef __attribute__((address_space(3))) unsigned int* las_ptr;

#define SCALE2 0.18033688f   /* 8^-1 * log2(e) */

// Fragment-tiled layout: T[blk128][kstep32][row128][32k]
//   flat = blk*65536 + ks*4096 + r*32 + kk

__device__ inline unsigned short f2bf(float f) {
    unsigned int u = __float_as_uint(f);
    u += 0x7fffu + ((u >> 16) & 1u);   // RNE
    return (unsigned short)(u >> 16);
}

// pack two fp32 -> two bf16 (truncation) in ONE v_perm
__device__ inline unsigned int pack_trunc(float lo, float hi) {
    return __builtin_amdgcn_perm(__float_as_uint(hi), __float_as_uint(lo), 0x07060302u);
}

// Raw v_exp_f32 (2^x) via the COMPILER-VISIBLE builtin (round-5 win: VALU
// busy halved vs OCML exp2f). Must NOT be inline asm: MFMA->VALU RAW hazard
// is software-managed and skipped for INLINEASM readers (round-4 corruption).
#if __has_builtin(__builtin_amdgcn_exp2f)
#define EXP2(x) __builtin_amdgcn_exp2f(x)
#else
#define EXP2(x) exp2f(x)
#endif

// LDS 16B-block swizzle for staged GEMM tiles: involution (XORs bits 3-5
// into bits 0-2, disjoint) => stage source block SWZB(d) into LDS block d,
// read global block g at LDS block SWZB(g).
#define SWZB(g) ((g) ^ (((g) >> 3) & 7))

// ---------------------------------------------------------------------------
// prep: convx (x -> bf16, fragment-tiled), transW (weights -> bf16 transposed
// + tiled), amask (adj -> u32 AND-words).
// ---------------------------------------------------------------------------
__global__ __launch_bounds__(256) void prep(
    const float* __restrict__ x, unsigned short* __restrict__ xt,
    const float* __restrict__ W0, const float* __restrict__ W1,
    const float* __restrict__ W2, const float* __restrict__ W3,
    unsigned short* __restrict__ Tqkv, unsigned short* __restrict__ To,
    const int* __restrict__ adj, unsigned int* __restrict__ amaskW)
{
    const int blk = blockIdx.x;
    const int t   = threadIdx.x;

    if (blk < 2048) {                       // ---- convx -> tiled ----
        const int i = (blk * 256 + t) * 8;
        const int m = i >> 9, k = i & 511;
        float4 a = *(const float4*)(x + i);
        float4 b = *(const float4*)(x + i + 4);
        ushort4 u0, u1;
        u0.x = f2bf(a.x); u0.y = f2bf(a.y); u0.z = f2bf(a.z); u0.w = f2bf(a.w);
        u1.x = f2bf(b.x); u1.y = f2bf(b.y); u1.z = f2bf(b.z); u1.w = f2bf(b.w);
        unsigned short* dst = xt + ((size_t)(m >> 7) * 65536)
                                 + (k >> 5) * 4096 + (m & 127) * 32 + (k & 31);
        *(ushort4*)dst       = u0;
        *(ushort4*)(dst + 4) = u1;
        return;
    }
    if (blk < 2304) {                       // ---- transW -> tiled ----
        __shared__ float tile[64][65];
        const int idx = blk - 2048;
        const int z = idx >> 6, rem = idx & 63;
        const float* W;
        switch (z) {
            case 0:  W = W0; break;
            case 1:  W = W1; break;
            case 2:  W = W2; break;
            default: W = W3; break;
        }
        unsigned short* T = (z < 3) ? Tqkv : To;
        const int ngbase  = (z < 3) ? z * 512 : 0;
        const int k0 = (rem & 7) * 64, n0 = (rem >> 3) * 64;
        const int r = t >> 6, c = t & 63;
#pragma unroll
        for (int rep = 0; rep < 16; ++rep) {
            const int row = rep * 4 + r;
            tile[row][c] = W[(size_t)(k0 + row) * NOUT + n0 + c];
        }
        __syncthreads();
        const int k  = k0 + c;
        const int ks = k >> 5, kk = k & 31;
#pragma unroll
        for (int rep = 0; rep < 16; ++rep) {
            const int row = rep * 4 + r;          // n within this matrix
            const int ng  = ngbase + n0 + row;
            T[((size_t)(ng >> 7) * 65536) + ks * 4096 + (ng & 127) * 32 + kk]
                = f2bf(tile[c][row]);
        }
        return;
    }
    // ---- amask: 4 u32 words (8 keys) per thread ----
    {
        const int gid  = (blk - 2304) * 256 + t;   // 0..524287
        const int w0   = gid * 4;
        const int qrow = w0 >> 10;
        const int wloc = w0 & 1023;
        const int kb0  = wloc * 2;
        int4 a0 = *(const int4*)(adj + (size_t)qrow * NN + kb0);
        int4 a1 = *(const int4*)(adj + (size_t)qrow * NN + kb0 + 4);
        uint4 m;
        m.x = (a0.x ? 0xFFFFu : 0u) | (a0.y ? 0xFFFF0000u : 0u);
        m.y = (a0.z ? 0xFFFFu : 0u) | (a0.w ? 0xFFFF0000u : 0u);
        m.z = (a1.x ? 0xFFFFu : 0u) | (a1.y ? 0xFFFF0000u : 0u);
        m.w = (a1.z ? 0xFFFFu : 0u) | (a1.w ? 0xFFFF0000u : 0u);
        *(uint4*)(amaskW + (size_t)qrow * 1024 + wloc) = m;
    }
}

// ---------------------------------------------------------------------------
// Staged GEMM (m97 structure): global_load_lds double-buffered K-loop.
// (r7: this took non-attn 131 -> 121 us. Kept verbatim.)
// ---------------------------------------------------------------------------
#define GTS_STAGE(ks, Ab, Bb, NB16)                                            \
    {                                                                          \
        const unsigned short* As_ = Asrc + (ks) * 4096;                        \
        const unsigned short* Bs_ = Bsrc + (ks) * 4096;                        \
        __builtin_amdgcn_global_load_lds(                                      \
            (gas_ptr)(As_ + (wave * 64 + lswz) * 8),                           \
            (las_ptr)((Ab) + wave * 512), 16, 0, 0);                           \
        __builtin_amdgcn_global_load_lds(                                      \
            (gas_ptr)(As_ + (256 + wave * 64 + lswz) * 8),                     \
            (las_ptr)((Ab) + 2048 + wave * 512), 16, 0, 0);                    \
        __builtin_amdgcn_global_load_lds(                                      \
            (gas_ptr)(Bs_ + (wave * 64 + lswz) * 8),                           \
            (las_ptr)((Bb) + wave * 512), 16, 0, 0);                           \
        if ((NB16) == 512)                                                     \
            __builtin_amdgcn_global_load_lds(                                  \
                (gas_ptr)(Bs_ + (256 + wave * 64 + lswz) * 8),                 \
                (las_ptr)((Bb) + 2048 + wave * 512), 16, 0, 0);                \
    }

#define GT_MFMA(Af, Bf, NTC)                                                   \
    _Pragma("unroll")                                                          \
    for (int mt = 0; mt < 4; ++mt)                                             \
        _Pragma("unroll")                                                      \
        for (int nt = 0; nt < NTC; ++nt)                                       \
            acc[mt][nt] = MFMA32(Af[mt], Bf[nt], acc[mt][nt]);

#define GTS_FRAGS(Ab, Bb, NTC)                                                 \
    bf16x8 aF[4], bF[NTC];                                                     \
    _Pragma("unroll")                                                          \
    for (int mt = 0; mt < 4; ++mt) aF[mt] = *(const bf16x8*)&(Ab)[aOff[mt]];   \
    _Pragma("unroll")                                                          \
    for (int nt = 0; nt < NTC; ++nt) bF[nt] = *(const bf16x8*)&(Bb)[bOff[nt]];

#define GTS_LOOP(NTC, NB16, sA0, sB0, sA1, sB1)                                \
    const int lswz = lane ^ ((lane >> 3) & 7);                                 \
    int aOff[4], bOff[NTC];                                                    \
    _Pragma("unroll")                                                          \
    for (int mt = 0; mt < 4; ++mt)                                             \
        aOff[mt] = SWZB((wm + mt * 16 + l16) * 4 + quad) * 8;                  \
    _Pragma("unroll")                                                          \
    for (int nt = 0; nt < NTC; ++nt)                                           \
        bOff[nt] = SWZB((wn + nt * 16 + l16) * 4 + quad) * 8;                  \
    f32x4 acc[4][NTC];                                                         \
    _Pragma("unroll")                                                          \
    for (int mt = 0; mt < 4; ++mt)                                             \
        _Pragma("unroll")                                                      \
        for (int nt = 0; nt < NTC; ++nt) acc[mt][nt] = (f32x4){0.f, 0.f, 0.f, 0.f}; \
    GTS_STAGE(0, sA0, sB0, NB16);                                              \
    for (int kk = 0; kk < 8; ++kk) {                                           \
        __syncthreads();                                                       \
        GTS_STAGE(2 * kk + 1, sA1, sB1, NB16);                                 \
        { GTS_FRAGS(sA0, sB0, NTC); GT_MFMA(aF, bF, NTC); }                    \
        __syncthreads();                                                       \
        if (kk < 7) GTS_STAGE(2 * kk + 2, sA0, sB0, NB16);                     \
        { GTS_FRAGS(sA1, sB1, NTC); GT_MFMA(aF, bF, NTC); }                    \
    }

// ---------------------------------------------------------------------------
// Fused QKV GEMM (staged). Coalesced epilogue via per-wave LDS round-trip.
// ---------------------------------------------------------------------------
__global__ __launch_bounds__(256, 3) void gemm_qkv(
    const unsigned short* __restrict__ Atil,
    const unsigned short* __restrict__ Wtil,
    const float* __restrict__ bq, const float* __restrict__ bk,
    const float* __restrict__ bv,
    unsigned short* __restrict__ qo, unsigned short* __restrict__ ko,
    unsigned short* __restrict__ vto)
{
    __shared__ unsigned short smem[16384];   // A0|B0|A1|B1 (32 KB), eps alias
    unsigned short* sA0 = smem;
    unsigned short* sB0 = smem + 4096;
    unsigned short* sA1 = smem + 8192;
    unsigned short* sB1 = smem + 12288;

    const int t = threadIdx.x, wave = t >> 6, lane = t & 63;
    const int quad = lane >> 4, l16 = lane & 15;
    const int n0 = blockIdx.x * 128, m0 = blockIdx.y * 128;
    const int wm = (wave & 1) * 64, wn = (wave >> 1) * 64;
    const unsigned short* Asrc = Atil + (size_t)blockIdx.y * 65536;
    const unsigned short* Bsrc = Wtil + (size_t)blockIdx.x * 65536;

    GTS_LOOP(4, 512, sA0, sB0, sA1, sB1);

    const int seg   = n0 >> 9;           // 0:q 1:k 2:v
    const int nloc0 = n0 & 511;
    const float* bp = (seg == 0) ? bq : (seg == 1) ? bk : bv;
    unsigned short* dst3 = (seg == 0) ? qo : (seg == 1) ? ko : vto;
    const int h = (nloc0 + wn) >> 6;     // wave's 64 cols = one head

    float bias4[4];
#pragma unroll
    for (int nt = 0; nt < 4; ++nt) bias4[nt] = bp[nloc0 + wn + nt * 16 + l16];

    __syncthreads();                     // staging reads done; alias eps
    unsigned short* Lo = smem + wave * 2560;
#pragma unroll
    for (int mt = 0; mt < 4; ++mt) {
        if (seg < 2) {
            // region [16 m][72 d-pad], C-layout scatter -> row-coalesced out
#pragma unroll
            for (int nt = 0; nt < 4; ++nt)
#pragma unroll
                for (int r = 0; r < 4; ++r) {
                    float val = acc[mt][nt][r] + bias4[nt];
                    if (seg == 0) val *= SCALE2;
                    Lo[(quad * 4 + r) * 72 + nt * 16 + l16] = f2bf(val);
                }
#pragma unroll
            for (int pass = 0; pass < 2; ++pass) {
                const int row = pass * 8 + (lane >> 3);
                const int mg  = m0 + wm + mt * 16 + row;
                const int bb  = mg >> 11, n = mg & (NN - 1);
                bf16x8 v = *(const bf16x8*)&Lo[row * 72 + (lane & 7) * 8];
                *(bf16x8*)(dst3 + ((size_t)(bb * NH + h) * NN + n) * HDIM
                           + (lane & 7) * 8) = v;
            }
        } else {
            // region [64 d][40-pad m], transposed scatter -> d-row out
#pragma unroll
            for (int nt = 0; nt < 4; ++nt)
#pragma unroll
                for (int r = 0; r < 4; ++r) {
                    const float val = acc[mt][nt][r] + bias4[nt];
                    Lo[(nt * 16 + l16) * 40 + quad * 4 + r] = f2bf(val);
                }
            const int d  = lane;
            const int mg = m0 + wm + mt * 16;
            const int bb = mg >> 11, n = mg & (NN - 1);
            unsigned short* dr = dst3 + ((size_t)(bb * NH + h) * HDIM + d) * NN + n;
            *(bf16x8*)dr       = *(const bf16x8*)&Lo[d * 40];
            *(bf16x8*)(dr + 8) = *(const bf16x8*)&Lo[d * 40 + 8];
        }
    }
}

// ---------------------------------------------------------------------------
// O-projection GEMM (staged): 128x64 tiles, out fp32 [8192,512]
// ---------------------------------------------------------------------------
__global__ __launch_bounds__(256, 3) void gemm_o(
    const unsigned short* __restrict__ Atil,
    const unsigned short* __restrict__ Wtil,
    const float* __restrict__ bias,
    float* __restrict__ C)
{
    __shared__ unsigned short smem[12288];   // A0(8K)|B0(4K)|A1(8K)|B1(4K)
    unsigned short* sA0 = smem;
    unsigned short* sB0 = smem + 4096;
    unsigned short* sA1 = smem + 6144;
    unsigned short* sB1 = smem + 10240;

    const int t = threadIdx.x, wave = t >> 6, lane = t & 63;
    const int quad = lane >> 4, l16 = lane & 15;
    const int n0 = blockIdx.x * 64, m0 = blockIdx.y * 128;
    const int wm = (wave & 1) * 64, wn = (wave >> 1) * 32;
    const unsigned short* Asrc = Atil + (size_t)blockIdx.y * 65536;
    const unsigned short* Bsrc = Wtil + (size_t)(n0 >> 7) * 65536 + (n0 & 64) * 32;

    GTS_LOOP(2, 256, sA0, sB0, sA1, sB1);

    float bias2[2];
#pragma unroll
    for (int nt = 0; nt < 2; ++nt) bias2[nt] = bias[n0 + wn + nt * 16 + l16];

#pragma unroll
    for (int mt = 0; mt < 4; ++mt)
#pragma unroll
        for (int nt = 0; nt < 2; ++nt) {
            const int col = n0 + wn + nt * 16 + l16;
#pragma unroll
            for (int r = 0; r < 4; ++r) {
                const int row = m0 + wm + mt * 16 + quad * 4 + r;
                C[(size_t)row * NOUT + col] = acc[mt][nt][r] + bias2[nt];
            }
        }
}

// ---------------------------------------------------------------------------
// MFMA flash attention — v6 (PROVEN best: 51.3us in r7, reproduced r10).
// Key-split wave pairs, 8 waves, 128 q/block, 64-key double-buffered phases
// (K AND V DMA-staged), builtin v_exp_f32. Seven structural variants all
// regressed: wider phases (r1), counted-vmcnt (r3), 64q/wave (r6),
// V-from-global (r8/r9), aux-packing (r10), QBLK=64 4-domain (r11 — the
// scheduler did NOT raise occupancy; 34.7% vs predicted 45%). This is the
// local optimum for the 2-barrier lockstep schedule.
// ---------------------------------------------------------------------------
__global__ __launch_bounds__(512, 4) void attn_mfma(
    const unsigned short* __restrict__ qg,
    const unsigned short* __restrict__ kg,
    const unsigned short* __restrict__ vt,
    const unsigned int* __restrict__ amask,   // [q][1024] u32 AND-words
    unsigned short* __restrict__ aot)
{
    // 36 KB: K/V double-buffer (32 KB) during loop; pair-reduction F +
    // epilogue Lo regions afterwards.
    __shared__ unsigned short smem[18432];
    unsigned short* Ka = smem;            // [64][64]
    unsigned short* Va = smem + 4096;
    unsigned short* Kb = smem + 8192;
    unsigned short* Vb = smem + 12288;

    const int t    = threadIdx.x;
    const int wave = t >> 6;
    const int lane = t & 63;
    const int quad = lane >> 4;
    const int l16  = lane & 15;
    const int pair = wave >> 1;          // 0..3: q-rows pair*32..+31
    const int hk   = wave & 1;           // key half within each 64-key tile

    const int qt = blockIdx.x, h = blockIdx.y, b = blockIdx.z;
    const int bh = b * NH + h;
    const int q0 = qt * 128;

    const unsigned short* kbase  = kg + (size_t)bh * NN * HDIM;
    const unsigned short* vtbase = vt + (size_t)bh * HDIM * NN;

    // DMA swizzle (16B blocks): physical blk = logical blk ^ (row & 7)
    const int drow = lane >> 3;
    const int dblk = (lane & 7) ^ drow;
    // key permutation: physical LDS row p holds logical key L(p)
    const int p  = wave * 8 + drow;
    const int Lp = (p & 32) + ((p >> 2) & 3) * 8 + ((p >> 4) & 1) * 4 + (p & 3);

    // fragment-read swizzle offsets
    const int sw  = l16 & 7;
    const int bo0 = (quad ^ sw) * 8;         // K d-chunk0 (16B)
    const int bo1 = bo0 ^ 32;                // K d-chunk1

#define ATT_ISSUE(kt, Kd, Vd)                                                  \
    {                                                                          \
        const int r0 = wave * 8;                                               \
        __builtin_amdgcn_global_load_lds(                                      \
            (gas_ptr)(kbase + (size_t)((kt) * 64 + Lp) * HDIM + dblk * 8),     \
            (las_ptr)(Kd + r0 * 64), 16, 0, 0);                                \
        __builtin_amdgcn_global_load_lds(                                      \
            (gas_ptr)(vtbase + (size_t)(r0 + drow) * NN + (kt) * 64 + dblk * 8), \
            (las_ptr)(Vd + r0 * 64), 16, 0, 0);                                \
    }

    // Q B-fragments for the pair's TWO 16-row q-groups
    const int myq0 = q0 + pair * 32 + l16;        // g=0
    const int myq1 = myq0 + 16;                   // g=1
    const unsigned short* qrow0 = qg + ((size_t)bh * NN + myq0) * HDIM;
    const unsigned short* qrow1 = qg + ((size_t)bh * NN + myq1) * HDIM;
    const bf16x8 bQ0g0 = *(const bf16x8*)(qrow0 + quad * 8);
    const bf16x8 bQ1g0 = *(const bf16x8*)(qrow0 + quad * 8 + 32);
    const bf16x8 bQ0g1 = *(const bf16x8*)(qrow1 + quad * 8);
    const bf16x8 bQ1g1 = *(const bf16x8*)(qrow1 + quad * 8 + 32);

    const unsigned int* mrow0 = amask + (size_t)myq0 * 1024 + quad * 4;
    const unsigned int* mrow1 = amask + (size_t)myq1 * 1024 + quad * 4;
#define MLOAD(kt, g) (*(const uint4*)(((g) ? mrow1 : mrow0) + (kt) * 32 + hk * 16))

    bf16x8 ones8;
#pragma unroll
    for (int j = 0; j < 8; ++j) ones8[j] = (short)0x3F80;

    f32x4 O[4][2];                // [dt 16-d group][q-group]
#pragma unroll
    for (int dt = 0; dt < 4; ++dt)
#pragma unroll
        for (int g = 0; g < 2; ++g) O[dt][g] = (f32x4){0.f, 0.f, 0.f, 0.f};
    f32x4 lacc[2];
    lacc[0] = (f32x4){0.f, 0.f, 0.f, 0.f};
    lacc[1] = (f32x4){0.f, 0.f, 0.f, 0.f};

    auto tile = [&](const unsigned short* Ks, const unsigned short* Vs,
                    uint4 mwg0, uint4 mwg1) {
        // K fragments for this wave's 32-key half, read ONCE, used for 2 q-groups
        bf16x8 aK[2][2];          // [kg 16-key group][d-chunk]
#pragma unroll
        for (int kg = 0; kg < 2; ++kg) {
            const int nt = hk * 2 + kg;
            aK[kg][0] = *(const bf16x8*)&Ks[(nt * 16 + l16) * 64 + bo0];
            aK[kg][1] = *(const bf16x8*)&Ks[(nt * 16 + l16) * 64 + bo1];
        }
        bf16x8 Pt[2];
#pragma unroll
        for (int g = 0; g < 2; ++g) {
            const uint4 mw = g ? mwg1 : mwg0;
            const bf16x8 q0f = g ? bQ0g1 : bQ0g0;
            const bf16x8 q1f = g ? bQ1g1 : bQ1g0;
            union { unsigned int u[4]; bf16x8 v; } cv;
#pragma unroll
            for (int kg = 0; kg < 2; ++kg) {
                f32x4 s = (f32x4){0.f, 0.f, 0.f, 0.f};
                s = MFMA32(aK[kg][0], q0f, s);
                s = MFMA32(aK[kg][1], q1f, s);
                const float p0 = EXP2(s[0]);
                const float p1 = EXP2(s[1]);
                const float p2 = EXP2(s[2]);
                const float p3 = EXP2(s[3]);
                cv.u[kg * 2 + 0] = pack_trunc(p0, p1) & (kg ? mw.z : mw.x);
                cv.u[kg * 2 + 1] = pack_trunc(p2, p3) & (kg ? mw.w : mw.y);
            }
            Pt[g] = cv.v;
            lacc[g] = MFMA32(ones8, Pt[g], lacc[g]);
        }
#pragma unroll
        for (int dt = 0; dt < 4; ++dt) {
            bf16x8 aV = *(const bf16x8*)
                &Vs[(dt * 16 + l16) * 64 + (((hk * 4 + quad) ^ sw) * 8)];
#pragma unroll
            for (int g = 0; g < 2; ++g)
                O[dt][g] = MFMA32(aV, Pt[g], O[dt][g]);
        }
    };

    uint4 mA0 = MLOAD(0, 0), mA1 = MLOAD(0, 1);
    uint4 mB0, mB1;
    ATT_ISSUE(0, Ka, Va);
    for (int kk = 0; kk < 16; ++kk) {
        __syncthreads();
        ATT_ISSUE(2 * kk + 1, Kb, Vb);
        mB0 = MLOAD(2 * kk + 1, 0); mB1 = MLOAD(2 * kk + 1, 1);
        tile(Ka, Va, mA0, mA1);
        __syncthreads();
        if (kk < 15) {
            ATT_ISSUE(2 * kk + 2, Ka, Va);
            mA0 = MLOAD(2 * kk + 2, 0); mA1 = MLOAD(2 * kk + 2, 1);
        }
        tile(Kb, Vb, mB0, mB1);
    }
    __syncthreads();   // all waves done reading K/V buffers

    // ---- cross-pair reduction: hk=1 partials -> LDS -> hk=0 accumulates ----
    // F region: [pair][lane][36 f32] (stride 36 words = 144 B, 16B-aligned)
    float* F   = (float*)smem;
    float* myF = F + ((size_t)pair * 64 + lane) * 36;
    if (hk == 1) {
#pragma unroll
        for (int dt = 0; dt < 4; ++dt)
#pragma unroll
            for (int g = 0; g < 2; ++g)
                *(f32x4*)(myF + dt * 8 + g * 4) = O[dt][g];
        myF[32] = lacc[0][0];
        myF[33] = lacc[1][0];
    }
    __syncthreads();
    float inv0 = 0.f, inv1 = 0.f;
    if (hk == 0) {
#pragma unroll
        for (int dt = 0; dt < 4; ++dt)
#pragma unroll
            for (int g = 0; g < 2; ++g) {
                const f32x4 o2 = *(const f32x4*)(myF + dt * 8 + g * 4);
                O[dt][g] += o2;
            }
        inv0 = 1.f / (lacc[0][0] + myF[32]);
        inv1 = 1.f / (lacc[1][0] + myF[33]);
    }
    __syncthreads();   // F consumed; smem reusable for Lo regions

    // ---- epilogue (hk=0 waves): O^T -> per-group LDS region -> tiled out ----
    if (hk == 0) {
#pragma unroll
        for (int g = 0; g < 2; ++g) {
            const float inv = g ? inv1 : inv0;
            unsigned short* Lo = smem + (pair * 2 + g) * 1152;
#pragma unroll
            for (int dt = 0; dt < 4; ++dt) {
                const float v0 = O[dt][g][0] * inv, v1 = O[dt][g][1] * inv;
                const float v2 = O[dt][g][2] * inv, v3 = O[dt][g][3] * inv;
                *(unsigned int*)&Lo[l16 * 72 + dt * 16 + quad * 4]     = pack_trunc(v0, v1);
                *(unsigned int*)&Lo[l16 * 72 + dt * 16 + quad * 4 + 2] = pack_trunc(v2, v3);
            }
            const int rr = lane >> 2;
            const int qq = q0 + pair * 32 + g * 16 + rr;
            const int m  = b * NN + qq;
            const int mb = m >> 7, r = m & 127;
#pragma unroll
            for (int i = 0; i < 2; ++i) {
                const int ch = (lane & 3) + 4 * i;            // 0..7 (d = ch*8)
                const int ks = h * 2 + (ch >> 2);
                bf16x8 val = *(const bf16x8*)&Lo[rr * 72 + ch * 8];
                *(bf16x8*)(aot + (size_t)mb * 65536 + ks * 4096 + r * 32 + (ch & 3) * 8) = val;
            }
        }
    }
#undef ATT_ISSUE
#undef MLOAD
}

// ---------------------------------------------------------------------------
extern "C" void kernel_launch(void* const* d_in, const int* in_sizes, int n_in,
                              void* d_out, int out_size, void* d_ws, size_t ws_size,
                              hipStream_t stream)
{
    const float* x   = (const float*)d_in[0];
    const int*   adj = (const int*)  d_in[1];
    const float* Wq  = (const float*)d_in[2];
    const float* bq  = (const float*)d_in[3];
    const float* Wk  = (const float*)d_in[4];
    const float* bk  = (const float*)d_in[5];
    const float* Wv  = (const float*)d_in[6];
    const float* bv  = (const float*)d_in[7];
    const float* Wo  = (const float*)d_in[8];
    const float* bo  = (const float*)d_in[9];
    float* out = (float*)d_out;

    const size_t qkv_elems = (size_t)NB * NH * NN * HDIM;   // 4,194,304
    unsigned short* xt    = (unsigned short*)d_ws;           // x tiled; reused as aot
    unsigned short* q     = xt   + qkv_elems;
    unsigned short* kb    = q    + qkv_elems;
    unsigned short* vtb   = kb   + qkv_elems;
    unsigned short* tWqkv = vtb  + qkv_elems;                // 1536x512 tiled
    unsigned short* tWo   = tWqkv + (size_t)3 * DD * NOUT;   // 512x512 tiled
    unsigned int*   amaskW = (unsigned int*)(tWo + (size_t)DD * NOUT);  // 8MB
    unsigned short* aot   = xt;                              // alias (xt dead after QKV)

    prep<<<dim3(4352), 256, 0, stream>>>(x, xt, Wq, Wk, Wv, Wo,
                                         tWqkv, tWo, adj, amaskW);

    gemm_qkv<<<dim3(12, 64), 256, 0, stream>>>(xt, tWqkv, bq, bk, bv, q, kb, vtb);

    attn_mfma<<<dim3(NN / 128, NH, NB), 512, 0, stream>>>(q, kb, vtb, amaskW, aot);

    gemm_o<<<dim3(8, 64), 256, 0, stream>>>(aot, tWo, bo, out);
}

// Round 13
// 169.517 us; speedup vs baseline: 1.1348x; 1.0267x over previous
//
#include <hip/hip_runtime.h>
#include <math.h>

#define NB   4
#define NN   2048
#define DD   512
#define NOUT 512
#define NH   8
#define HDIM 64

typedef __attribute__((ext_vector_type(4))) short bf16x4;
typedef __attribute__((ext_vector_type(8))) short bf16x8;
typedef __attribute__((ext_vector_type(4))) float f32x4;
#define MFMA32(a, b, c)  __builtin_amdgcn_mfma_f32_16x16x32_bf16(a, b, c, 0, 0, 0)

typedef const __attribute__((address_space(1))) unsigned int* gas_ptr;
typedef __attribute__((address_space(3))) unsigned int* las_ptr;

#define SCALE2 0.18033688f   /* 8^-1 * log2(e) */

// Fragment-tiled layout: T[blk128][kstep32][row128][32k]
//   flat = blk*65536 + ks*4096 + r*32 + kk

__device__ inline unsigned short f2bf(float f) {
    unsigned int u = __float_as_uint(f);
    u += 0x7fffu + ((u >> 16) & 1u);   // RNE
    return (unsigned short)(u >> 16);
}

// pack two fp32 -> two bf16 (truncation) in ONE v_perm
__device__ inline unsigned int pack_trunc(float lo, float hi) {
    return __builtin_amdgcn_perm(__float_as_uint(hi), __float_as_uint(lo), 0x07060302u);
}

// Raw v_exp_f32 (2^x) via the COMPILER-VISIBLE builtin (round-5 win: VALU
// busy halved vs OCML exp2f). Must NOT be inline asm: MFMA->VALU RAW hazard
// is software-managed and skipped for INLINEASM readers (round-4 corruption).
#if __has_builtin(__builtin_amdgcn_exp2f)
#define EXP2(x) __builtin_amdgcn_exp2f(x)
#else
#define EXP2(x) exp2f(x)
#endif

// LDS 16B-block swizzle for staged GEMM tiles: involution (XORs bits 3-5
// into bits 0-2, disjoint) => stage source block SWZB(d) into LDS block d,
// read global block g at LDS block SWZB(g).
#define SWZB(g) ((g) ^ (((g) >> 3) & 7))

// ---------------------------------------------------------------------------
// prep: convx (x -> bf16, fragment-tiled), transW (weights -> bf16 transposed
// + tiled), amask (adj -> u32 AND-words).
// ---------------------------------------------------------------------------
__global__ __launch_bounds__(256) void prep(
    const float* __restrict__ x, unsigned short* __restrict__ xt,
    const float* __restrict__ W0, const float* __restrict__ W1,
    const float* __restrict__ W2, const float* __restrict__ W3,
    unsigned short* __restrict__ Tqkv, unsigned short* __restrict__ To,
    const int* __restrict__ adj, unsigned int* __restrict__ amaskW)
{
    const int blk = blockIdx.x;
    const int t   = threadIdx.x;

    if (blk < 2048) {                       // ---- convx -> tiled ----
        const int i = (blk * 256 + t) * 8;
        const int m = i >> 9, k = i & 511;
        float4 a = *(const float4*)(x + i);
        float4 b = *(const float4*)(x + i + 4);
        ushort4 u0, u1;
        u0.x = f2bf(a.x); u0.y = f2bf(a.y); u0.z = f2bf(a.z); u0.w = f2bf(a.w);
        u1.x = f2bf(b.x); u1.y = f2bf(b.y); u1.z = f2bf(b.z); u1.w = f2bf(b.w);
        unsigned short* dst = xt + ((size_t)(m >> 7) * 65536)
                                 + (k >> 5) * 4096 + (m & 127) * 32 + (k & 31);
        *(ushort4*)dst       = u0;
        *(ushort4*)(dst + 4) = u1;
        return;
    }
    if (blk < 2304) {                       // ---- transW -> tiled ----
        __shared__ float tile[64][65];
        const int idx = blk - 2048;
        const int z = idx >> 6, rem = idx & 63;
        const float* W;
        switch (z) {
            case 0:  W = W0; break;
            case 1:  W = W1; break;
            case 2:  W = W2; break;
            default: W = W3; break;
        }
        unsigned short* T = (z < 3) ? Tqkv : To;
        const int ngbase  = (z < 3) ? z * 512 : 0;
        const int k0 = (rem & 7) * 64, n0 = (rem >> 3) * 64;
        const int r = t >> 6, c = t & 63;
#pragma unroll
        for (int rep = 0; rep < 16; ++rep) {
            const int row = rep * 4 + r;
            tile[row][c] = W[(size_t)(k0 + row) * NOUT + n0 + c];
        }
        __syncthreads();
        const int k  = k0 + c;
        const int ks = k >> 5, kk = k & 31;
#pragma unroll
        for (int rep = 0; rep < 16; ++rep) {
            const int row = rep * 4 + r;          // n within this matrix
            const int ng  = ngbase + n0 + row;
            T[((size_t)(ng >> 7) * 65536) + ks * 4096 + (ng & 127) * 32 + kk]
                = f2bf(tile[c][row]);
        }
        return;
    }
    // ---- amask: 4 u32 words (8 keys) per thread ----
    {
        const int gid  = (blk - 2304) * 256 + t;   // 0..524287
        const int w0   = gid * 4;
        const int qrow = w0 >> 10;
        const int wloc = w0 & 1023;
        const int kb0  = wloc * 2;
        int4 a0 = *(const int4*)(adj + (size_t)qrow * NN + kb0);
        int4 a1 = *(const int4*)(adj + (size_t)qrow * NN + kb0 + 4);
        uint4 m;
        m.x = (a0.x ? 0xFFFFu : 0u) | (a0.y ? 0xFFFF0000u : 0u);
        m.y = (a0.z ? 0xFFFFu : 0u) | (a0.w ? 0xFFFF0000u : 0u);
        m.z = (a1.x ? 0xFFFFu : 0u) | (a1.y ? 0xFFFF0000u : 0u);
        m.w = (a1.z ? 0xFFFFu : 0u) | (a1.w ? 0xFFFF0000u : 0u);
        *(uint4*)(amaskW + (size_t)qrow * 1024 + wloc) = m;
    }
}

// ---------------------------------------------------------------------------
// Staged GEMM (m97 structure): global_load_lds double-buffered K-loop.
// (r7: this took non-attn 131 -> 121 us. Kept verbatim.)
// ---------------------------------------------------------------------------
#define GTS_STAGE(ks, Ab, Bb, NB16)                                            \
    {                                                                          \
        const unsigned short* As_ = Asrc + (ks) * 4096;                        \
        const unsigned short* Bs_ = Bsrc + (ks) * 4096;                        \
        __builtin_amdgcn_global_load_lds(                                      \
            (gas_ptr)(As_ + (wave * 64 + lswz) * 8),                           \
            (las_ptr)((Ab) + wave * 512), 16, 0, 0);                           \
        __builtin_amdgcn_global_load_lds(                                      \
            (gas_ptr)(As_ + (256 + wave * 64 + lswz) * 8),                     \
            (las_ptr)((Ab) + 2048 + wave * 512), 16, 0, 0);                    \
        __builtin_amdgcn_global_load_lds(                                      \
            (gas_ptr)(Bs_ + (wave * 64 + lswz) * 8),                           \
            (las_ptr)((Bb) + wave * 512), 16, 0, 0);                           \
        if ((NB16) == 512)                                                     \
            __builtin_amdgcn_global_load_lds(                                  \
                (gas_ptr)(Bs_ + (256 + wave * 64 + lswz) * 8),                 \
                (las_ptr)((Bb) + 2048 + wave * 512), 16, 0, 0);                \
    }

#define GT_MFMA(Af, Bf, NTC)                                                   \
    _Pragma("unroll")                                                          \
    for (int mt = 0; mt < 4; ++mt)                                             \
        _Pragma("unroll")                                                      \
        for (int nt = 0; nt < NTC; ++nt)                                       \
            acc[mt][nt] = MFMA32(Af[mt], Bf[nt], acc[mt][nt]);

#define GTS_FRAGS(Ab, Bb, NTC)                                                 \
    bf16x8 aF[4], bF[NTC];                                                     \
    _Pragma("unroll")                                                          \
    for (int mt = 0; mt < 4; ++mt) aF[mt] = *(const bf16x8*)&(Ab)[aOff[mt]];   \
    _Pragma("unroll")                                                          \
    for (int nt = 0; nt < NTC; ++nt) bF[nt] = *(const bf16x8*)&(Bb)[bOff[nt]];

#define GTS_LOOP(NTC, NB16, sA0, sB0, sA1, sB1)                                \
    const int lswz = lane ^ ((lane >> 3) & 7);                                 \
    int aOff[4], bOff[NTC];                                                    \
    _Pragma("unroll")                                                          \
    for (int mt = 0; mt < 4; ++mt)                                             \
        aOff[mt] = SWZB((wm + mt * 16 + l16) * 4 + quad) * 8;                  \
    _Pragma("unroll")                                                          \
    for (int nt = 0; nt < NTC; ++nt)                                           \
        bOff[nt] = SWZB((wn + nt * 16 + l16) * 4 + quad) * 8;                  \
    f32x4 acc[4][NTC];                                                         \
    _Pragma("unroll")                                                          \
    for (int mt = 0; mt < 4; ++mt)                                             \
        _Pragma("unroll")                                                      \
        for (int nt = 0; nt < NTC; ++nt) acc[mt][nt] = (f32x4){0.f, 0.f, 0.f, 0.f}; \
    GTS_STAGE(0, sA0, sB0, NB16);                                              \
    for (int kk = 0; kk < 8; ++kk) {                                           \
        __syncthreads();                                                       \
        GTS_STAGE(2 * kk + 1, sA1, sB1, NB16);                                 \
        { GTS_FRAGS(sA0, sB0, NTC); GT_MFMA(aF, bF, NTC); }                    \
        __syncthreads();                                                       \
        if (kk < 7) GTS_STAGE(2 * kk + 2, sA0, sB0, NB16);                     \
        { GTS_FRAGS(sA1, sB1, NTC); GT_MFMA(aF, bF, NTC); }                    \
    }

// ---------------------------------------------------------------------------
// Fused QKV GEMM (staged). Coalesced epilogue via per-wave LDS round-trip.
// ---------------------------------------------------------------------------
__global__ __launch_bounds__(256, 3) void gemm_qkv(
    const unsigned short* __restrict__ Atil,
    const unsigned short* __restrict__ Wtil,
    const float* __restrict__ bq, const float* __restrict__ bk,
    const float* __restrict__ bv,
    unsigned short* __restrict__ qo, unsigned short* __restrict__ ko,
    unsigned short* __restrict__ vto)
{
    __shared__ unsigned short smem[16384];   // A0|B0|A1|B1 (32 KB), eps alias
    unsigned short* sA0 = smem;
    unsigned short* sB0 = smem + 4096;
    unsigned short* sA1 = smem + 8192;
    unsigned short* sB1 = smem + 12288;

    const int t = threadIdx.x, wave = t >> 6, lane = t & 63;
    const int quad = lane >> 4, l16 = lane & 15;
    const int n0 = blockIdx.x * 128, m0 = blockIdx.y * 128;
    const int wm = (wave & 1) * 64, wn = (wave >> 1) * 64;
    const unsigned short* Asrc = Atil + (size_t)blockIdx.y * 65536;
    const unsigned short* Bsrc = Wtil + (size_t)blockIdx.x * 65536;

    GTS_LOOP(4, 512, sA0, sB0, sA1, sB1);

    const int seg   = n0 >> 9;           // 0:q 1:k 2:v
    const int nloc0 = n0 & 511;
    const float* bp = (seg == 0) ? bq : (seg == 1) ? bk : bv;
    unsigned short* dst3 = (seg == 0) ? qo : (seg == 1) ? ko : vto;
    const int h = (nloc0 + wn) >> 6;     // wave's 64 cols = one head

    float bias4[4];
#pragma unroll
    for (int nt = 0; nt < 4; ++nt) bias4[nt] = bp[nloc0 + wn + nt * 16 + l16];

    __syncthreads();                     // staging reads done; alias eps
    unsigned short* Lo = smem + wave * 2560;
#pragma unroll
    for (int mt = 0; mt < 4; ++mt) {
        if (seg < 2) {
            // region [16 m][72 d-pad], C-layout scatter -> row-coalesced out
#pragma unroll
            for (int nt = 0; nt < 4; ++nt)
#pragma unroll
                for (int r = 0; r < 4; ++r) {
                    float val = acc[mt][nt][r] + bias4[nt];
                    if (seg == 0) val *= SCALE2;
                    Lo[(quad * 4 + r) * 72 + nt * 16 + l16] = f2bf(val);
                }
#pragma unroll
            for (int pass = 0; pass < 2; ++pass) {
                const int row = pass * 8 + (lane >> 3);
                const int mg  = m0 + wm + mt * 16 + row;
                const int bb  = mg >> 11, n = mg & (NN - 1);
                bf16x8 v = *(const bf16x8*)&Lo[row * 72 + (lane & 7) * 8];
                *(bf16x8*)(dst3 + ((size_t)(bb * NH + h) * NN + n) * HDIM
                           + (lane & 7) * 8) = v;
            }
        } else {
            // region [64 d][40-pad m], transposed scatter -> d-row out
#pragma unroll
            for (int nt = 0; nt < 4; ++nt)
#pragma unroll
                for (int r = 0; r < 4; ++r) {
                    const float val = acc[mt][nt][r] + bias4[nt];
                    Lo[(nt * 16 + l16) * 40 + quad * 4 + r] = f2bf(val);
                }
            const int d  = lane;
            const int mg = m0 + wm + mt * 16;
            const int bb = mg >> 11, n = mg & (NN - 1);
            unsigned short* dr = dst3 + ((size_t)(bb * NH + h) * HDIM + d) * NN + n;
            *(bf16x8*)dr       = *(const bf16x8*)&Lo[d * 40];
            *(bf16x8*)(dr + 8) = *(const bf16x8*)&Lo[d * 40 + 8];
        }
    }
}

// ---------------------------------------------------------------------------
// O-projection GEMM (staged): 128x64 tiles, out fp32 [8192,512]
// ---------------------------------------------------------------------------
__global__ __launch_bounds__(256, 3) void gemm_o(
    const unsigned short* __restrict__ Atil,
    const unsigned short* __restrict__ Wtil,
    const float* __restrict__ bias,
    float* __restrict__ C)
{
    __shared__ unsigned short smem[12288];   // A0(8K)|B0(4K)|A1(8K)|B1(4K)
    unsigned short* sA0 = smem;
    unsigned short* sB0 = smem + 4096;
    unsigned short* sA1 = smem + 6144;
    unsigned short* sB1 = smem + 10240;

    const int t = threadIdx.x, wave = t >> 6, lane = t & 63;
    const int quad = lane >> 4, l16 = lane & 15;
    const int n0 = blockIdx.x * 64, m0 = blockIdx.y * 128;
    const int wm = (wave & 1) * 64, wn = (wave >> 1) * 32;
    const unsigned short* Asrc = Atil + (size_t)blockIdx.y * 65536;
    const unsigned short* Bsrc = Wtil + (size_t)(n0 >> 7) * 65536 + (n0 & 64) * 32;

    GTS_LOOP(2, 256, sA0, sB0, sA1, sB1);

    float bias2[2];
#pragma unroll
    for (int nt = 0; nt < 2; ++nt) bias2[nt] = bias[n0 + wn + nt * 16 + l16];

#pragma unroll
    for (int mt = 0; mt < 4; ++mt)
#pragma unroll
        for (int nt = 0; nt < 2; ++nt) {
            const int col = n0 + wn + nt * 16 + l16;
#pragma unroll
            for (int r = 0; r < 4; ++r) {
                const int row = m0 + wm + mt * 16 + quad * 4 + r;
                C[(size_t)row * NOUT + col] = acc[mt][nt][r] + bias2[nt];
            }
        }
}

// ---------------------------------------------------------------------------
// MFMA flash attention — v6 structure (proven 51.3-52.1us) + T5 s_setprio
// around the PV MFMA cluster. ISOLATED test: r0's setprio was confounded
// with the regressing 128-key phase change and never ran on v6 alone.
// Mechanism (m191, attn +4-7%): v6 runs 2 INDEPENDENT blocks/CU whose
// phases drift — when this block's waves enter the pure-MFMA PV region
// while the co-block issues DMA/exp2, priority-1 keeps the matrix pipe fed.
// (m190's GEMM null was 4-wave lockstep, single barrier domain — different
// regime.) Everything else byte-identical to r12.
// ---------------------------------------------------------------------------
__global__ __launch_bounds__(512, 4) void attn_mfma(
    const unsigned short* __restrict__ qg,
    const unsigned short* __restrict__ kg,
    const unsigned short* __restrict__ vt,
    const unsigned int* __restrict__ amask,   // [q][1024] u32 AND-words
    unsigned short* __restrict__ aot)
{
    // 36 KB: K/V double-buffer (32 KB) during loop; pair-reduction F +
    // epilogue Lo regions afterwards.
    __shared__ unsigned short smem[18432];
    unsigned short* Ka = smem;            // [64][64]
    unsigned short* Va = smem + 4096;
    unsigned short* Kb = smem + 8192;
    unsigned short* Vb = smem + 12288;

    const int t    = threadIdx.x;
    const int wave = t >> 6;
    const int lane = t & 63;
    const int quad = lane >> 4;
    const int l16  = lane & 15;
    const int pair = wave >> 1;          // 0..3: q-rows pair*32..+31
    const int hk   = wave & 1;           // key half within each 64-key tile

    const int qt = blockIdx.x, h = blockIdx.y, b = blockIdx.z;
    const int bh = b * NH + h;
    const int q0 = qt * 128;

    const unsigned short* kbase  = kg + (size_t)bh * NN * HDIM;
    const unsigned short* vtbase = vt + (size_t)bh * HDIM * NN;

    // DMA swizzle (16B blocks): physical blk = logical blk ^ (row & 7)
    const int drow = lane >> 3;
    const int dblk = (lane & 7) ^ drow;
    // key permutation: physical LDS row p holds logical key L(p)
    const int p  = wave * 8 + drow;
    const int Lp = (p & 32) + ((p >> 2) & 3) * 8 + ((p >> 4) & 1) * 4 + (p & 3);

    // fragment-read swizzle offsets
    const int sw  = l16 & 7;
    const int bo0 = (quad ^ sw) * 8;         // K d-chunk0 (16B)
    const int bo1 = bo0 ^ 32;                // K d-chunk1

#define ATT_ISSUE(kt, Kd, Vd)                                                  \
    {                                                                          \
        const int r0 = wave * 8;                                               \
        __builtin_amdgcn_global_load_lds(                                      \
            (gas_ptr)(kbase + (size_t)((kt) * 64 + Lp) * HDIM + dblk * 8),     \
            (las_ptr)(Kd + r0 * 64), 16, 0, 0);                                \
        __builtin_amdgcn_global_load_lds(                                      \
            (gas_ptr)(vtbase + (size_t)(r0 + drow) * NN + (kt) * 64 + dblk * 8), \
            (las_ptr)(Vd + r0 * 64), 16, 0, 0);                                \
    }

    // Q B-fragments for the pair's TWO 16-row q-groups
    const int myq0 = q0 + pair * 32 + l16;        // g=0
    const int myq1 = myq0 + 16;                   // g=1
    const unsigned short* qrow0 = qg + ((size_t)bh * NN + myq0) * HDIM;
    const unsigned short* qrow1 = qg + ((size_t)bh * NN + myq1) * HDIM;
    const bf16x8 bQ0g0 = *(const bf16x8*)(qrow0 + quad * 8);
    const bf16x8 bQ1g0 = *(const bf16x8*)(qrow0 + quad * 8 + 32);
    const bf16x8 bQ0g1 = *(const bf16x8*)(qrow1 + quad * 8);
    const bf16x8 bQ1g1 = *(const bf16x8*)(qrow1 + quad * 8 + 32);

    const unsigned int* mrow0 = amask + (size_t)myq0 * 1024 + quad * 4;
    const unsigned int* mrow1 = amask + (size_t)myq1 * 1024 + quad * 4;
#define MLOAD(kt, g) (*(const uint4*)(((g) ? mrow1 : mrow0) + (kt) * 32 + hk * 16))

    bf16x8 ones8;
#pragma unroll
    for (int j = 0; j < 8; ++j) ones8[j] = (short)0x3F80;

    f32x4 O[4][2];                // [dt 16-d group][q-group]
#pragma unroll
    for (int dt = 0; dt < 4; ++dt)
#pragma unroll
        for (int g = 0; g < 2; ++g) O[dt][g] = (f32x4){0.f, 0.f, 0.f, 0.f};
    f32x4 lacc[2];
    lacc[0] = (f32x4){0.f, 0.f, 0.f, 0.f};
    lacc[1] = (f32x4){0.f, 0.f, 0.f, 0.f};

    auto tile = [&](const unsigned short* Ks, const unsigned short* Vs,
                    uint4 mwg0, uint4 mwg1) {
        // K fragments for this wave's 32-key half, read ONCE, used for 2 q-groups
        bf16x8 aK[2][2];          // [kg 16-key group][d-chunk]
#pragma unroll
        for (int kg = 0; kg < 2; ++kg) {
            const int nt = hk * 2 + kg;
            aK[kg][0] = *(const bf16x8*)&Ks[(nt * 16 + l16) * 64 + bo0];
            aK[kg][1] = *(const bf16x8*)&Ks[(nt * 16 + l16) * 64 + bo1];
        }
        bf16x8 Pt[2];
#pragma unroll
        for (int g = 0; g < 2; ++g) {
            const uint4 mw = g ? mwg1 : mwg0;
            const bf16x8 q0f = g ? bQ0g1 : bQ0g0;
            const bf16x8 q1f = g ? bQ1g1 : bQ1g0;
            union { unsigned int u[4]; bf16x8 v; } cv;
#pragma unroll
            for (int kg = 0; kg < 2; ++kg) {
                f32x4 s = (f32x4){0.f, 0.f, 0.f, 0.f};
                s = MFMA32(aK[kg][0], q0f, s);
                s = MFMA32(aK[kg][1], q1f, s);
                const float p0 = EXP2(s[0]);
                const float p1 = EXP2(s[1]);
                const float p2 = EXP2(s[2]);
                const float p3 = EXP2(s[3]);
                cv.u[kg * 2 + 0] = pack_trunc(p0, p1) & (kg ? mw.z : mw.x);
                cv.u[kg * 2 + 1] = pack_trunc(p2, p3) & (kg ? mw.w : mw.y);
            }
            Pt[g] = cv.v;
            lacc[g] = MFMA32(ones8, Pt[g], lacc[g]);
        }
        // T5: pure-MFMA PV cluster under priority 1 (co-block overlap bias)
        __builtin_amdgcn_s_setprio(1);
#pragma unroll
        for (int dt = 0; dt < 4; ++dt) {
            bf16x8 aV = *(const bf16x8*)
                &Vs[(dt * 16 + l16) * 64 + (((hk * 4 + quad) ^ sw) * 8)];
#pragma unroll
            for (int g = 0; g < 2; ++g)
                O[dt][g] = MFMA32(aV, Pt[g], O[dt][g]);
        }
        __builtin_amdgcn_s_setprio(0);
    };

    uint4 mA0 = MLOAD(0, 0), mA1 = MLOAD(0, 1);
    uint4 mB0, mB1;
    ATT_ISSUE(0, Ka, Va);
    for (int kk = 0; kk < 16; ++kk) {
        __syncthreads();
        ATT_ISSUE(2 * kk + 1, Kb, Vb);
        mB0 = MLOAD(2 * kk + 1, 0); mB1 = MLOAD(2 * kk + 1, 1);
        tile(Ka, Va, mA0, mA1);
        __syncthreads();
        if (kk < 15) {
            ATT_ISSUE(2 * kk + 2, Ka, Va);
            mA0 = MLOAD(2 * kk + 2, 0); mA1 = MLOAD(2 * kk + 2, 1);
        }
        tile(Kb, Vb, mB0, mB1);
    }
    __syncthreads();   // all waves done reading K/V buffers

    // ---- cross-pair reduction: hk=1 partials -> LDS -> hk=0 accumulates ----
    // F region: [pair][lane][36 f32] (stride 36 words = 144 B, 16B-aligned)
    float* F   = (float*)smem;
    float* myF = F + ((size_t)pair * 64 + lane) * 36;
    if (hk == 1) {
#pragma unroll
        for (int dt = 0; dt < 4; ++dt)
#pragma unroll
            for (int g = 0; g < 2; ++g)
                *(f32x4*)(myF + dt * 8 + g * 4) = O[dt][g];
        myF[32] = lacc[0][0];
        myF[33] = lacc[1][0];
    }
    __syncthreads();
    float inv0 = 0.f, inv1 = 0.f;
    if (hk == 0) {
#pragma unroll
        for (int dt = 0; dt < 4; ++dt)
#pragma unroll
            for (int g = 0; g < 2; ++g) {
                const f32x4 o2 = *(const f32x4*)(myF + dt * 8 + g * 4);
                O[dt][g] += o2;
            }
        inv0 = 1.f / (lacc[0][0] + myF[32]);
        inv1 = 1.f / (lacc[1][0] + myF[33]);
    }
    __syncthreads();   // F consumed; smem reusable for Lo regions

    // ---- epilogue (hk=0 waves): O^T -> per-group LDS region -> tiled out ----
    if (hk == 0) {
#pragma unroll
        for (int g = 0; g < 2; ++g) {
            const float inv = g ? inv1 : inv0;
            unsigned short* Lo = smem + (pair * 2 + g) * 1152;
#pragma unroll
            for (int dt = 0; dt < 4; ++dt) {
                const float v0 = O[dt][g][0] * inv, v1 = O[dt][g][1] * inv;
                const float v2 = O[dt][g][2] * inv, v3 = O[dt][g][3] * inv;
                *(unsigned int*)&Lo[l16 * 72 + dt * 16 + quad * 4]     = pack_trunc(v0, v1);
                *(unsigned int*)&Lo[l16 * 72 + dt * 16 + quad * 4 + 2] = pack_trunc(v2, v3);
            }
            const int rr = lane >> 2;
            const int qq = q0 + pair * 32 + g * 16 + rr;
            const int m  = b * NN + qq;
            const int mb = m >> 7, r = m & 127;
#pragma unroll
            for (int i = 0; i < 2; ++i) {
                const int ch = (lane & 3) + 4 * i;            // 0..7 (d = ch*8)
                const int ks = h * 2 + (ch >> 2);
                bf16x8 val = *(const bf16x8*)&Lo[rr * 72 + ch * 8];
                *(bf16x8*)(aot + (size_t)mb * 65536 + ks * 4096 + r * 32 + (ch & 3) * 8) = val;
            }
        }
    }
#undef ATT_ISSUE
#undef MLOAD
}

// ---------------------------------------------------------------------------
extern "C" void kernel_launch(void* const* d_in, const int* in_sizes, int n_in,
                              void* d_out, int out_size, void* d_ws, size_t ws_size,
                              hipStream_t stream)
{
    const float* x   = (const float*)d_in[0];
    const int*   adj = (const int*)  d_in[1];
    const float* Wq  = (const float*)d_in[2];
    const float* bq  = (const float*)d_in[3];
    const float* Wk  = (const float*)d_in[4];
    const float* bk  = (const float*)d_in[5];
    const float* Wv  = (const float*)d_in[6];
    const float* bv  = (const float*)d_in[7];
    const float* Wo  = (const float*)d_in[8];
    const float* bo  = (const float*)d_in[9];
    float* out = (float*)d_out;

    const size_t qkv_elems = (size_t)NB * NH * NN * HDIM;   // 4,194,304
    unsigned short* xt    = (unsigned short*)d_ws;           // x tiled; reused as aot
    unsigned short* q     = xt   + qkv_elems;
    unsigned short* kb    = q    + qkv_elems;
    unsigned short* vtb   = kb   + qkv_elems;
    unsigned short* tWqkv = vtb  + qkv_elems;                // 1536x512 tiled
    unsigned short* tWo   = tWqkv + (size_t)3 * DD * NOUT;   // 512x512 tiled
    unsigned int*   amaskW = (unsigned int*)(tWo + (size_t)DD * NOUT);  // 8MB
    unsigned short* aot   = xt;                              // alias (xt dead after QKV)

    prep<<<dim3(4352), 256, 0, stream>>>(x, xt, Wq, Wk, Wv, Wo,
                                         tWqkv, tWo, adj, amaskW);

    gemm_qkv<<<dim3(12, 64), 256, 0, stream>>>(xt, tWqkv, bq, bk, bv, q, kb, vtb);

    attn_mfma<<<dim3(NN / 128, NH, NB), 512, 0, stream>>>(q, kb, vtb, amaskW, aot);

    gemm_o<<<dim3(8, 64), 256, 0, stream>>>(aot, tWo, bo, out);
}